// Round 2
// baseline (433.122 us; speedup 1.0000x reference)
//
#include <hip/hip_runtime.h>

// CrossNet: B=500000 rows, D=128, L=4.
//   x0 = inputs; xl = x0; for i: xl = x0 * dot(xl, w_i) + b_i + xl
//
// Algebraic collapse: xl_i = c_i * x0 + d_i, where
//   d_i = b_0 + ... + b_{i-1}              (row-INDEPENDENT vector)
//   t_i = w_i . x0                         (one dot vs x0 per layer)
//   u_i = w_i . d_i                        (row-independent scalar)
//   c_0 = 1;  c_{i+1} = c_i*(1 + t_i) + u_i
//   out = c_4 * x0 + d_4
// => all 4 dots are against the SAME vector x0: one parallel reduction pass
//    (3-deep shfl butterfly over 8-lane row groups) instead of 4 serial ones.
//
// Layout: 8 lanes/row, 16 elts/lane as 4x float4 at float4-index (j + 8k).
// Each wave-load = 64 lanes x 16B = 16 fully-used cache lines (8 rows x 128B).
// 4 independent loads in flight per thread; DS pressure 3 ops / 4KB.

typedef float vf4 __attribute__((ext_vector_type(4)));

#define CN_D 128
#define CN_L 4

__device__ __forceinline__ float dot4(vf4 a, vf4 b) {
    return fmaf(a.x, b.x, fmaf(a.y, b.y, fmaf(a.z, b.z, a.w * b.w)));
}

__device__ __forceinline__ vf4 fma4s(vf4 x, float c, vf4 d) {
    vf4 r;
    r.x = fmaf(x.x, c, d.x);
    r.y = fmaf(x.y, c, d.y);
    r.z = fmaf(x.z, c, d.z);
    r.w = fmaf(x.w, c, d.w);
    return r;
}

__global__ __launch_bounds__(256, 4) void crossnet_kernel(
    const float* __restrict__ inputs,
    const float* __restrict__ kernels,
    const float* __restrict__ biases,
    float* __restrict__ out,
    int nrows)
{
    const int j   = threadIdx.x & 7;           // sub-lane within 8-lane row group
    const int grp = threadIdx.x >> 3;          // row group within block (0..31)
    const int rows_per_blk = blockDim.x >> 3;  // 32

    // Weight fragments: w[i][k] = float4 at index (j + 8k) of layer i. 64 VGPRs.
    vf4 w[CN_L][4];
#pragma unroll
    for (int i = 0; i < CN_L; ++i)
#pragma unroll
        for (int k = 0; k < 4; ++k)
            w[i][k] = ((const vf4*)(kernels + i * CN_D))[j + 8 * k];

    // Bias-derived constants: d (running partial-bias-sum fragment) and u[i].
    float u[CN_L];
    u[0] = 0.f;  // d_0 = 0
    vf4 d[4];
#pragma unroll
    for (int k = 0; k < 4; ++k)
        d[k] = ((const vf4*)(biases))[j + 8 * k];          // d_1 = b_0
#pragma unroll
    for (int i = 1; i < CN_L; ++i) {
        float p = dot4(w[i][0], d[0]) + dot4(w[i][1], d[1])
                + dot4(w[i][2], d[2]) + dot4(w[i][3], d[3]);
        p += __shfl_xor(p, 1);
        p += __shfl_xor(p, 2);
        p += __shfl_xor(p, 4);
        u[i] = p;                                          // u_i = w_i . d_i
#pragma unroll
        for (int k = 0; k < 4; ++k)
            d[k] += ((const vf4*)(biases + i * CN_D))[j + 8 * k];
    }
    // d now holds d_4 = b0+b1+b2+b3 fragment.

    for (long long row = (long long)blockIdx.x * rows_per_blk + grp;
         row < nrows;
         row += (long long)gridDim.x * rows_per_blk)
    {
        const vf4* xp = (const vf4*)(inputs + row * CN_D);
        vf4 x0 = xp[j];
        vf4 x1 = xp[j + 8];
        vf4 x2 = xp[j + 16];
        vf4 x3 = xp[j + 24];

        // Four partial dots, all against x0 (independent FMA chains).
        float t0 = dot4(x0, w[0][0]) + dot4(x1, w[0][1]) + dot4(x2, w[0][2]) + dot4(x3, w[0][3]);
        float t1 = dot4(x0, w[1][0]) + dot4(x1, w[1][1]) + dot4(x2, w[1][2]) + dot4(x3, w[1][3]);
        float t2 = dot4(x0, w[2][0]) + dot4(x1, w[2][1]) + dot4(x2, w[2][2]) + dot4(x3, w[2][3]);
        float t3 = dot4(x0, w[3][0]) + dot4(x1, w[3][1]) + dot4(x2, w[3][2]) + dot4(x3, w[3][3]);

        // One 3-step butterfly over the 8-lane group, 4 values in parallel.
        t0 += __shfl_xor(t0, 1); t1 += __shfl_xor(t1, 1); t2 += __shfl_xor(t2, 1); t3 += __shfl_xor(t3, 1);
        t0 += __shfl_xor(t0, 2); t1 += __shfl_xor(t1, 2); t2 += __shfl_xor(t2, 2); t3 += __shfl_xor(t3, 2);
        t0 += __shfl_xor(t0, 4); t1 += __shfl_xor(t1, 4); t2 += __shfl_xor(t2, 4); t3 += __shfl_xor(t3, 4);

        // Scalar recurrence: c_{i+1} = c_i*(1+t_i) + u_i   (u_0 = 0)
        float c = 1.f + t0;
        c = fmaf(c, t1, c) + u[1];
        c = fmaf(c, t2, c) + u[2];
        c = fmaf(c, t3, c) + u[3];

        // out = c * x0 + d_4 ; nontemporal: don't evict L3-warm input.
        vf4* op = (vf4*)(out + row * CN_D);
        __builtin_nontemporal_store(fma4s(x0, c, d[0]), &op[j]);
        __builtin_nontemporal_store(fma4s(x1, c, d[1]), &op[j + 8]);
        __builtin_nontemporal_store(fma4s(x2, c, d[2]), &op[j + 16]);
        __builtin_nontemporal_store(fma4s(x3, c, d[3]), &op[j + 24]);
    }
}

extern "C" void kernel_launch(void* const* d_in, const int* in_sizes, int n_in,
                              void* d_out, int out_size, void* d_ws, size_t ws_size,
                              hipStream_t stream) {
    const float* inputs  = (const float*)d_in[0];
    const float* kernels = (const float*)d_in[1];
    const float* biases  = (const float*)d_in[2];
    float* out = (float*)d_out;

    const int nrows = in_sizes[0] / CN_D;  // 500000

    const int block = 256;                 // 32 rows per block per sweep
    long long nblk = ((long long)nrows + 31) / 32;
    const int grid = (int)(nblk < 2048 ? nblk : 2048);  // ~7.6 grid-stride sweeps

    crossnet_kernel<<<grid, block, 0, stream>>>(inputs, kernels, biases, out, nrows);
}